// Round 7
// baseline (367.596 us; speedup 1.0000x reference)
//
#include <hip/hip_runtime.h>
#include <hip/hip_bf16.h>
#include <stdint.h>

// Galerkin self-attention, fused single-kernel pipeline:
//   out = seq @ (wq.T @ blockdiag_h(kv[b,h]) @ wo.T) + bo
//   kv[b,h] = (1/S) * LN(k)_h^T @ LN(v)_h,   k = seq@wk.T, v = seq@wv.T
// v7: ONE persistent kernel (512 blocks = 2/CU exactly, __launch_bounds__(256,2),
//     64KB LDS) with device-scope grid barriers replacing 4 inter-kernel graph
//     gaps (~3-4us each). Phases = r6 kernels verbatim: prep | kv | red | wc | out.
//     Barrier counters (16B in ws) zeroed via captured hipMemsetAsync.
// ws layout (bytes):
//   0        wkf bf16 fragment-major [w8][kk][n][lane][8]
//   131072   wvf bf16 fragment-major
//   262144   wqT bf16 [256 i][256 j]
//   524288   kvf f32 [4 b][4 h][4096 frag]
//   1310720  wcf bf16 fragment-major [b][o6][kk][n][lane][8]
//   1835008  bar: 4 x u32 grid-barrier counters
// d_out doubles as scratch for P = bf16 partials [4 b][128 p][4 h][4096 frag]
// (16.8MB of the 33.5MB output buffer); the final phase overwrites all of d_out.

#define EMBED 256
#define SEQ   8192
#define LN_EPS 1e-5f
#define NBLK  512

using bf16x8 = __attribute__((ext_vector_type(8))) short;
using bf16x4 = __attribute__((ext_vector_type(4))) short;
using f32x4  = __attribute__((ext_vector_type(4))) float;

static __device__ __forceinline__ short f2bf(float f) {
  __hip_bfloat16 h = __float2bfloat16(f);
  return __builtin_bit_cast(short, h);
}
static __device__ __forceinline__ float bf2f(uint32_t u) {
  return __uint_as_float(u << 16);
}

#define MFMA16(a, b, c) __builtin_amdgcn_mfma_f32_16x16x32_bf16((a), (b), (c), 0, 0, 0)

// device-scope grid barrier: all NBLK blocks are co-resident by construction
// (512 blocks = 2/CU * 256 CU; launch_bounds(256,2) caps VGPR at 256; 64KB LDS -> 2/CU)
static __device__ __forceinline__ void gridbar(unsigned* cnt) {
  __syncthreads();
  if (threadIdx.x == 0) {
    __threadfence();                                  // release our writes (agent scope)
    __hip_atomic_fetch_add(cnt, 1u, __ATOMIC_RELEASE, __HIP_MEMORY_SCOPE_AGENT);
    unsigned v;
    do {
      __builtin_amdgcn_s_sleep(1);
      v = __hip_atomic_load(cnt, __ATOMIC_ACQUIRE, __HIP_MEMORY_SCOPE_AGENT);
    } while (v < (unsigned)NBLK);
    __threadfence();                                  // acquire others' writes
  }
  __syncthreads();
}

// Stage ROWS x 256 fp32 rows -> bf16 LDS [ROWS][256], rows 512B, byte^=(row&7)<<4
template <int ROWS>
static __device__ __forceinline__ void stage_x(char* smem, const float* __restrict__ src, int tid) {
#pragma unroll
  for (int i = 0; i < ROWS / 8; ++i) {
    int g = tid + i * 256;              // 16B-granule index
    int row = g >> 5, c16 = g & 31;
    const f32x4* p = (const f32x4*)(src + row * EMBED + c16 * 8);
    f32x4 f0 = p[0], f1 = p[1];
    bf16x8 v;
    v[0] = f2bf(f0[0]); v[1] = f2bf(f0[1]); v[2] = f2bf(f0[2]); v[3] = f2bf(f0[3]);
    v[4] = f2bf(f1[0]); v[5] = f2bf(f1[1]); v[6] = f2bf(f1[2]); v[7] = f2bf(f1[3]);
    *(bf16x8*)(smem + row * 512 + ((c16 * 16) ^ ((row & 7) << 4))) = v;
  }
}

__global__ __launch_bounds__(256, 2)
void gka_mega(const float* seq, const float* wq, const float* wk, const float* wv,
              const float* wo, const float* bo,
              const float* lkg, const float* lkb, const float* lvg, const float* lvb,
              unsigned short* wkf, unsigned short* wvf, unsigned short* wqt,
              float* kvf, unsigned short* wcf, void* dout, unsigned* bar) {
  __shared__ char smem[65536];
  const int blk = blockIdx.x;
  const int tid = threadIdx.x;
  const int lane = tid & 63;
  const int wid = tid >> 6;
  const int l15 = lane & 15, l4 = lane >> 4, l7 = lane & 7;
  unsigned short* P = (unsigned short*)dout;   // kv partials scratch (overwritten by P4)
  float* out = (float*)dout;

  // ================= P0: prep (blocks 0..79) =================
  if (blk < 64) {                         // wk/wv -> fragment-major bf16x8 per thread
    int g = (blk & 31) * 256 + tid;       // [0, 8192)
    const float* W = (blk < 32) ? wk : wv;
    unsigned short* D = (blk < 32) ? wkf : wvf;
    int w8 = g >> 11, kk = (g >> 8) & 7, n = (g >> 6) & 3, ln = g & 63;
    int row = w8 * 64 + n * 16 + (ln & 15);
    int c0 = kk * 32 + (ln >> 4) * 8;
    const f32x4* p = (const f32x4*)(W + row * 256 + c0);
    f32x4 f0 = p[0], f1 = p[1];
    bf16x8 v;
    v[0] = f2bf(f0[0]); v[1] = f2bf(f0[1]); v[2] = f2bf(f0[2]); v[3] = f2bf(f0[3]);
    v[4] = f2bf(f1[0]); v[5] = f2bf(f1[1]); v[6] = f2bf(f1[2]); v[7] = f2bf(f1[3]);
    *(bf16x8*)(D + g * 8) = v;
  } else if (blk < 80) {                  // 16 blocks: wqt[i][j] = wq[j][i] tile transpose
    unsigned short* T = (unsigned short*)smem;   // [64][66]
    int t = blk - 64, ti = t >> 2, tj = t & 3;
#pragma unroll
    for (int it = 0; it < 4; ++it) {
      int g = tid + it * 256;
      int jl = g >> 4, g4 = g & 15;
      f32x4 f = *(const f32x4*)(wq + (tj * 64 + jl) * 256 + ti * 64 + g4 * 4);
#pragma unroll
      for (int q = 0; q < 4; ++q) T[jl * 66 + g4 * 4 + q] = (unsigned short)f2bf(f[q]);
    }
    __syncthreads();
#pragma unroll
    for (int it = 0; it < 2; ++it) {
      int g = tid + it * 256;
      int il = g >> 3, j8 = g & 7;
      bf16x8 v;
#pragma unroll
      for (int q = 0; q < 8; ++q) v[q] = (short)T[(j8 * 8 + q) * 66 + il];
      *(bf16x8*)(wqt + (ti * 64 + il) * 256 + tj * 64 + j8 * 8) = v;
    }
  }
  gridbar(bar + 0);

  // ================= P1: kv (all 512 blocks, 64 tokens each) =================
  {
    const int b = blk >> 7;
    const int ptile = blk & 127;

    stage_x<64>(smem, seq + (size_t)(b * SEQ + ptile * 64) * EMBED, tid);
    __syncthreads();

    f32x4 acck[4][4], accv[4][4];
#pragma unroll
    for (int m = 0; m < 4; ++m)
#pragma unroll
      for (int n = 0; n < 4; ++n) { acck[m][n] = (f32x4)0.0f; accv[m][n] = (f32x4)0.0f; }

#pragma unroll
    for (int kk = 0; kk < 8; ++kk) {      // K = 256, steps of 32
      bf16x8 af[4], bwk[4], bwv[4];
#pragma unroll
      for (int m = 0; m < 4; ++m) {
        int row = m * 16 + l15;
        af[m] = *(const bf16x8*)(smem + row * 512 + ((kk * 64 + l4 * 16) ^ (l7 << 4)));
      }
#pragma unroll
      for (int n = 0; n < 4; ++n) {       // fragment-major: 512B coalesced per wave
        size_t off = (((wid * 8 + kk) * 4 + n) * 64 + lane) << 3;
        bwk[n] = *(const bf16x8*)(wkf + off);
        bwv[n] = *(const bf16x8*)(wvf + off);
      }
#pragma unroll
      for (int m = 0; m < 4; ++m)
#pragma unroll
        for (int n = 0; n < 4; ++n) {
          acck[m][n] = MFMA16(af[m], bwk[n], acck[m][n]);
          accv[m][n] = MFMA16(af[m], bwv[n], accv[m][n]);
        }
    }

    __syncthreads();                      // all x-tile LDS reads done

    // LN; write kT -> smem+32K, vT -> smem (over x)
#pragma unroll
    for (int mat = 0; mat < 2; ++mat) {
      const f32x4 (*acc)[4] = mat ? accv : acck;
      const float* gp = mat ? lvg : lkg;
      const float* bp = mat ? lvb : lkb;
      float gv[4], bv[4];
#pragma unroll
      for (int n = 0; n < 4; ++n) { gv[n] = gp[n * 16 + l15]; bv[n] = bp[n * 16 + l15]; }
      char* T = smem + (mat ? 0 : 32768) + wid * 8192;  // [64 d|e][64 s], 128B rows
#pragma unroll
      for (int m = 0; m < 4; ++m) {
        float mu[4], rs[4];
#pragma unroll
        for (int r = 0; r < 4; ++r) {
          float s1 = 0.f, s2 = 0.f;
#pragma unroll
          for (int n = 0; n < 4; ++n) { float x = acc[m][n][r]; s1 += x; s2 += x * x; }
#pragma unroll
          for (int msk = 1; msk < 16; msk <<= 1) {
            s1 += __shfl_xor(s1, msk);
            s2 += __shfl_xor(s2, msk);
          }
          mu[r] = s1 * (1.f / 64.f);
          float var = s2 * (1.f / 64.f) - mu[r] * mu[r];
          rs[r] = rsqrtf(var + LN_EPS);
        }
#pragma unroll
        for (int n = 0; n < 4; ++n) {
          bf16x4 pk;
#pragma unroll
          for (int r = 0; r < 4; ++r)
            pk[r] = f2bf((acc[m][n][r] - mu[r]) * rs[r] * gv[n] + bv[n]);
          int d = n * 16 + l15;           // d&7 == l7
          int sb = m * 32 + l4 * 8;
          *(bf16x4*)(T + d * 128 + (sb ^ (l7 << 4))) = pk;
        }
      }
    }

    __syncthreads();                      // kT + vT ready

    // kv outer product: wave = head
    f32x4 a2[4][4];
#pragma unroll
    for (int fd = 0; fd < 4; ++fd)
#pragma unroll
      for (int n = 0; n < 4; ++n) a2[fd][n] = (f32x4)0.0f;

#pragma unroll
    for (int kk = 0; kk < 2; ++kk) {
      bf16x8 ak[4], bv2[4];
#pragma unroll
      for (int fd = 0; fd < 4; ++fd) {
        int d = fd * 16 + l15;
        ak[fd] = *(const bf16x8*)(smem + 32768 + wid * 8192 + d * 128 +
                                  ((kk * 64 + l4 * 16) ^ (l7 << 4)));
      }
#pragma unroll
      for (int n = 0; n < 4; ++n) {
        int e = n * 16 + l15;
        bv2[n] = *(const bf16x8*)(smem + wid * 8192 + e * 128 +
                                  ((kk * 64 + l4 * 16) ^ (l7 << 4)));
      }
#pragma unroll
      for (int fd = 0; fd < 4; ++fd)
#pragma unroll
        for (int n = 0; n < 4; ++n)
          a2[fd][n] = MFMA16(ak[fd], bv2[n], a2[fd][n]);
    }

    unsigned short* Ph = P + ((size_t)((b * 128 + ptile) * 4 + wid) << 12);
#pragma unroll
    for (int fd = 0; fd < 4; ++fd)
#pragma unroll
      for (int n = 0; n < 4; ++n) {
        bf16x4 pk;
#pragma unroll
        for (int r = 0; r < 4; ++r) pk[r] = f2bf(a2[fd][n][r]);
        *(bf16x4*)(Ph + (fd * 4 + n) * 256 + lane * 4) = pk;
      }
  }
  gridbar(bar + 1);

  // ================= P2: red (all 512 blocks) =================
  {
    int gtid = blk * 256 + tid;           // 131072 = 16384 quads x 8 chunks
    int chunk = gtid & 7;
    int qid = gtid >> 3;
    int b = qid >> 12, h = (qid >> 10) & 3, t4 = qid & 1023;
    const unsigned short* p0 = P + ((size_t)(b * 512 + h) << 12) + t4 * 4;
    float s0 = 0.f, s1 = 0.f, s2 = 0.f, s3 = 0.f;
#pragma unroll
    for (int s = 0; s < 16; ++s) {
      int p = chunk * 16 + s;
      uint2 u = *(const uint2*)(p0 + ((size_t)p << 14));
      s0 += bf2f(u.x & 0xffffu); s1 += bf2f(u.x >> 16);
      s2 += bf2f(u.y & 0xffffu); s3 += bf2f(u.y >> 16);
    }
#pragma unroll
    for (int msk = 1; msk < 8; msk <<= 1) {
      s0 += __shfl_xor(s0, msk); s1 += __shfl_xor(s1, msk);
      s2 += __shfl_xor(s2, msk); s3 += __shfl_xor(s3, msk);
    }
    if (chunk == 0) {
      f32x4 r; r[0] = s0; r[1] = s1; r[2] = s2; r[3] = s3;
      *(f32x4*)(kvf + (qid << 2)) = r;
    }
  }
  gridbar(bar + 2);

  // ================= P3: wc (blocks 0..15 = 4b x 4 o-quarter) =================
  if (blk < 16) {
    const int b = blk >> 2, oq = blk & 3;
    const float invS = 1.f / (float)SEQ;
    char* M1 = smem;                      // [64 o_loc][256 j] bf16, 512B rows, swz

    // phase A: wave = head wj; M1T[o_loc][wj*64+d] = sum_e kv[b,wj,d,e]/S * wo[o][wj*64+e]
    {
      const int wj = wid;
      const float* kvh = kvf + ((b * 4 + wj) << 12);
      f32x4 acc[4][4];
#pragma unroll
      for (int m = 0; m < 4; ++m)
#pragma unroll
        for (int n = 0; n < 4; ++n) acc[m][n] = (f32x4)0.0f;

#pragma unroll
      for (int kk = 0; kk < 2; ++kk) {    // K = 64 (e)
        bf16x8 af[4], bw[4];
#pragma unroll
        for (int m = 0; m < 4; ++m) {
          int base = (m * 4 + kk * 2 + (l4 >> 1)) * 256 +
                     ((l15 >> 2) * 16 + (l4 & 1) * 8) * 4 + (l15 & 3);
          bf16x8 v;
#pragma unroll
          for (int j = 0; j < 8; ++j) v[j] = f2bf(kvh[base + j * 4] * invS);
          af[m] = v;
        }
#pragma unroll
        for (int n = 0; n < 4; ++n) {
          int o = oq * 64 + n * 16 + l15;
          const f32x4* wp = (const f32x4*)(wo + (size_t)o * 256 + wj * 64 + kk * 32 + l4 * 8);
          f32x4 w0 = wp[0], w1 = wp[1];
          bf16x8 v;
          v[0] = f2bf(w0[0]); v[1] = f2bf(w0[1]); v[2] = f2bf(w0[2]); v[3] = f2bf(w0[3]);
          v[4] = f2bf(w1[0]); v[5] = f2bf(w1[1]); v[6] = f2bf(w1[2]); v[7] = f2bf(w1[3]);
          bw[n] = v;
        }
#pragma unroll
        for (int m = 0; m < 4; ++m)
#pragma unroll
          for (int n = 0; n < 4; ++n)
            acc[m][n] = MFMA16(af[m], bw[n], acc[m][n]);
      }
#pragma unroll
      for (int m = 0; m < 4; ++m)
#pragma unroll
        for (int n = 0; n < 4; ++n) {
          int row = n * 16 + l15;         // o_loc
          int jb = (wj * 64 + m * 16 + l4 * 4) * 2;
          bf16x4 pk;
#pragma unroll
          for (int r = 0; r < 4; ++r) pk[r] = f2bf(acc[m][n][r]);
          *(bf16x4*)(M1 + row * 512 + (jb ^ ((row & 7) << 4))) = pk;
        }
    }

    __syncthreads();

    // phase B: wave = i-range wi; Wc[i][o] = sum_j wqT[i][j] * M1T[o_loc][j]
    {
      const int wi = wid;
      f32x4 acc[4][4];
#pragma unroll
      for (int m = 0; m < 4; ++m)
#pragma unroll
        for (int n = 0; n < 4; ++n) acc[m][n] = (f32x4)0.0f;

#pragma unroll
      for (int kk = 0; kk < 8; ++kk) {    // K = 256 (j)
        bf16x8 af[4], bw[4];
#pragma unroll
        for (int m = 0; m < 4; ++m) {
          int i = wi * 64 + m * 16 + l15;
          af[m] = *(const bf16x8*)(wqt + i * 256 + kk * 32 + l4 * 8);
        }
#pragma unroll
        for (int n = 0; n < 4; ++n) {
          int row = n * 16 + l15;
          bw[n] = *(const bf16x8*)(M1 + row * 512 +
                                   ((kk * 64 + l4 * 16) ^ ((row & 7) << 4)));
        }
#pragma unroll
        for (int m = 0; m < 4; ++m)
#pragma unroll
          for (int n = 0; n < 4; ++n)
            acc[m][n] = MFMA16(af[m], bw[n], acc[m][n]);
      }
      const int o6 = oq;
#pragma unroll
      for (int m = 0; m < 4; ++m)
#pragma unroll
        for (int n = 0; n < 4; ++n) {
          int kko = wi * 2 + (m >> 1);
          int laneo = ((m & 1) * 2 + (l4 >> 1)) * 16 + l15;
          int jo = (l4 & 1) * 4;
          bf16x4 pk;
#pragma unroll
          for (int r = 0; r < 4; ++r) pk[r] = f2bf(acc[m][n][r]);
          *(bf16x4*)(wcf + ((size_t)b << 16) +
                     (((((o6 * 8 + kko) * 4 + n) * 64) + laneo) << 3) + jo) = pk;
        }
    }
  }
  gridbar(bar + 3);

  // ================= P4: out (all 512 blocks, 64-row tiles) =================
  {
    const int b = blk >> 7;
    const int srow = (blk & 127) * 64;

    stage_x<64>(smem, seq + (size_t)(b * SEQ + srow) * EMBED, tid);

    const unsigned short* Wf = wcf + ((size_t)b << 16);
    float bov[4];
#pragma unroll
    for (int n = 0; n < 4; ++n) bov[n] = bo[wid * 64 + n * 16 + l15];

    f32x4 acc[4][4];
#pragma unroll
    for (int m = 0; m < 4; ++m)
#pragma unroll
      for (int n = 0; n < 4; ++n) acc[m][n] = (f32x4)0.0f;

    __syncthreads();

#pragma unroll
    for (int kk = 0; kk < 8; ++kk) {      // K = 256
      bf16x8 af[4], bw[4];
#pragma unroll
      for (int m = 0; m < 4; ++m) {
        int row = m * 16 + l15;
        af[m] = *(const bf16x8*)(smem + row * 512 + ((kk * 64 + l4 * 16) ^ (l7 << 4)));
      }
#pragma unroll
      for (int n = 0; n < 4; ++n)         // coalesced 512B per wave, L2-resident
        bw[n] = *(const bf16x8*)(Wf + ((((wid * 8 + kk) * 4 + n) * 64 + lane) << 3));
#pragma unroll
      for (int m = 0; m < 4; ++m)
#pragma unroll
        for (int n = 0; n < 4; ++n)
          acc[m][n] = MFMA16(af[m], bw[n], acc[m][n]);
    }

    float* dst = out + (size_t)(b * SEQ + srow) * EMBED;
#pragma unroll
    for (int m = 0; m < 4; ++m)
#pragma unroll
      for (int n = 0; n < 4; ++n)
#pragma unroll
        for (int r = 0; r < 4; ++r)
          dst[(size_t)(m * 16 + l4 * 4 + r) * EMBED + wid * 64 + n * 16 + l15] =
              acc[m][n][r] + bov[n];
  }
}

extern "C" void kernel_launch(void* const* d_in, const int* in_sizes, int n_in,
                              void* d_out, int out_size, void* d_ws, size_t ws_size,
                              hipStream_t stream) {
  const float* seq = (const float*)d_in[0];
  const float* wq  = (const float*)d_in[1];
  const float* wk  = (const float*)d_in[2];
  const float* wv  = (const float*)d_in[3];
  const float* wo  = (const float*)d_in[4];
  const float* bo  = (const float*)d_in[5];
  const float* lkg = (const float*)d_in[6];
  const float* lkb = (const float*)d_in[7];
  const float* lvg = (const float*)d_in[8];
  const float* lvb = (const float*)d_in[9];
  char* ws = (char*)d_ws;

  unsigned short* wkf = (unsigned short*)(ws + 0);
  unsigned short* wvf = (unsigned short*)(ws + 131072);
  unsigned short* wqt = (unsigned short*)(ws + 262144);
  float*          kvf = (float*)(ws + 524288);
  unsigned short* wcf = (unsigned short*)(ws + 1310720);
  unsigned*       bar = (unsigned*)(ws + 1835008);

  hipMemsetAsync(bar, 0, 16, stream);     // zero grid-barrier counters (captured node)
  gka_mega<<<NBLK, 256, 0, stream>>>(seq, wq, wk, wv, wo, bo, lkg, lkb, lvg, lvb,
                                     wkf, wvf, wqt, kvf, wcf, d_out, bar);
}

// Round 8
// 193.998 us; speedup vs baseline: 1.8948x; 1.8948x over previous
//
#include <hip/hip_runtime.h>
#include <hip/hip_bf16.h>
#include <stdint.h>

// Galerkin self-attention, fused single-kernel pipeline:
//   out = seq @ (wq.T @ blockdiag_h(kv[b,h]) @ wo.T) + bo
//   kv[b,h] = (1/S) * LN(k)_h^T @ LN(v)_h,   k = seq@wk.T, v = seq@wv.T
// v8: v7 with the grid barrier FIXED (r7 spun on ACQUIRE loads -> buffer_inv
//     per poll -> L2 invalidation storm, ~90us/barrier). Now: RELAXED spin +
//     s_sleep(16), single ACQUIRE load on exit, RELEASE fetch_add on arrival,
//     128B-padded counters. Also: P4's seq tile pre-staged into the free LDS
//     half during P2 (kT region dead after P1) - removes serial stage latency.
// ws layout (bytes):
//   0        wkf bf16 fragment-major [w8][kk][n][lane][8]
//   131072   wvf bf16 fragment-major
//   262144   wqT bf16 [256 i][256 j]
//   524288   kvf f32 [4 b][4 h][4096 frag]
//   1310720  wcf bf16 fragment-major [b][o6][kk][n][lane][8]
//   1835008  bar: 4 x u32 grid-barrier counters, 128B apart (512B total)
// d_out doubles as scratch for P = bf16 partials [4 b][128 p][4 h][4096 frag]
// (16.8MB of the 33.5MB output buffer); the final phase overwrites all of d_out.

#define EMBED 256
#define SEQ   8192
#define LN_EPS 1e-5f
#define NBLK  512

using bf16x8 = __attribute__((ext_vector_type(8))) short;
using bf16x4 = __attribute__((ext_vector_type(4))) short;
using f32x4  = __attribute__((ext_vector_type(4))) float;

static __device__ __forceinline__ short f2bf(float f) {
  __hip_bfloat16 h = __float2bfloat16(f);
  return __builtin_bit_cast(short, h);
}
static __device__ __forceinline__ float bf2f(uint32_t u) {
  return __uint_as_float(u << 16);
}

#define MFMA16(a, b, c) __builtin_amdgcn_mfma_f32_16x16x32_bf16((a), (b), (c), 0, 0, 0)

// device-scope grid barrier: all NBLK blocks co-resident by construction
// (512 blocks = 2/CU * 256 CU; 64KB LDS -> exactly 2 blocks/CU).
// RELEASE arrival (one wbL2 per block), RELAXED spin (no cache ops per poll),
// one ACQUIRE load on exit (one L2 inv per block).
static __device__ __forceinline__ void gridbar(unsigned* cnt) {
  __syncthreads();
  if (threadIdx.x == 0) {
    __hip_atomic_fetch_add(cnt, 1u, __ATOMIC_RELEASE, __HIP_MEMORY_SCOPE_AGENT);
    while (__hip_atomic_load(cnt, __ATOMIC_RELAXED, __HIP_MEMORY_SCOPE_AGENT) <
           (unsigned)NBLK)
      __builtin_amdgcn_s_sleep(16);
    (void)__hip_atomic_load(cnt, __ATOMIC_ACQUIRE, __HIP_MEMORY_SCOPE_AGENT);
  }
  __syncthreads();
}

// Stage ROWS x 256 fp32 rows -> bf16 LDS [ROWS][256], rows 512B, byte^=(row&7)<<4
template <int ROWS>
static __device__ __forceinline__ void stage_x(char* smem, const float* __restrict__ src, int tid) {
#pragma unroll
  for (int i = 0; i < ROWS / 8; ++i) {
    int g = tid + i * 256;              // 16B-granule index
    int row = g >> 5, c16 = g & 31;
    const f32x4* p = (const f32x4*)(src + row * EMBED + c16 * 8);
    f32x4 f0 = p[0], f1 = p[1];
    bf16x8 v;
    v[0] = f2bf(f0[0]); v[1] = f2bf(f0[1]); v[2] = f2bf(f0[2]); v[3] = f2bf(f0[3]);
    v[4] = f2bf(f1[0]); v[5] = f2bf(f1[1]); v[6] = f2bf(f1[2]); v[7] = f2bf(f1[3]);
    *(bf16x8*)(smem + row * 512 + ((c16 * 16) ^ ((row & 7) << 4))) = v;
  }
}

__global__ __launch_bounds__(256, 2)
void gka_mega(const float* seq, const float* wq, const float* wk, const float* wv,
              const float* wo, const float* bo,
              const float* lkg, const float* lkb, const float* lvg, const float* lvb,
              unsigned short* wkf, unsigned short* wvf, unsigned short* wqt,
              float* kvf, unsigned short* wcf, void* dout, unsigned* bar) {
  __shared__ char smem[65536];
  const int blk = blockIdx.x;
  const int tid = threadIdx.x;
  const int lane = tid & 63;
  const int wid = tid >> 6;
  const int l15 = lane & 15, l4 = lane >> 4, l7 = lane & 7;
  unsigned short* P = (unsigned short*)dout;   // kv partials scratch (overwritten by P4)
  float* out = (float*)dout;

  // ================= P0: prep (blocks 0..79) =================
  if (blk < 64) {                         // wk/wv -> fragment-major bf16x8 per thread
    int g = (blk & 31) * 256 + tid;       // [0, 8192)
    const float* W = (blk < 32) ? wk : wv;
    unsigned short* D = (blk < 32) ? wkf : wvf;
    int w8 = g >> 11, kk = (g >> 8) & 7, n = (g >> 6) & 3, ln = g & 63;
    int row = w8 * 64 + n * 16 + (ln & 15);
    int c0 = kk * 32 + (ln >> 4) * 8;
    const f32x4* p = (const f32x4*)(W + row * 256 + c0);
    f32x4 f0 = p[0], f1 = p[1];
    bf16x8 v;
    v[0] = f2bf(f0[0]); v[1] = f2bf(f0[1]); v[2] = f2bf(f0[2]); v[3] = f2bf(f0[3]);
    v[4] = f2bf(f1[0]); v[5] = f2bf(f1[1]); v[6] = f2bf(f1[2]); v[7] = f2bf(f1[3]);
    *(bf16x8*)(D + g * 8) = v;
  } else if (blk < 80) {                  // 16 blocks: wqt[i][j] = wq[j][i] tile transpose
    unsigned short* T = (unsigned short*)smem;   // [64][66]
    int t = blk - 64, ti = t >> 2, tj = t & 3;
#pragma unroll
    for (int it = 0; it < 4; ++it) {
      int g = tid + it * 256;
      int jl = g >> 4, g4 = g & 15;
      f32x4 f = *(const f32x4*)(wq + (tj * 64 + jl) * 256 + ti * 64 + g4 * 4);
#pragma unroll
      for (int q = 0; q < 4; ++q) T[jl * 66 + g4 * 4 + q] = (unsigned short)f2bf(f[q]);
    }
    __syncthreads();
#pragma unroll
    for (int it = 0; it < 2; ++it) {
      int g = tid + it * 256;
      int il = g >> 3, j8 = g & 7;
      bf16x8 v;
#pragma unroll
      for (int q = 0; q < 8; ++q) v[q] = (short)T[(j8 * 8 + q) * 66 + il];
      *(bf16x8*)(wqt + (ti * 64 + il) * 256 + tj * 64 + j8 * 8) = v;
    }
  }
  gridbar(bar + 0);

  // ================= P1: kv (all 512 blocks, 64 tokens each) =================
  {
    const int b = blk >> 7;
    const int ptile = blk & 127;

    stage_x<64>(smem, seq + (size_t)(b * SEQ + ptile * 64) * EMBED, tid);
    __syncthreads();

    f32x4 acck[4][4], accv[4][4];
#pragma unroll
    for (int m = 0; m < 4; ++m)
#pragma unroll
      for (int n = 0; n < 4; ++n) { acck[m][n] = (f32x4)0.0f; accv[m][n] = (f32x4)0.0f; }

#pragma unroll
    for (int kk = 0; kk < 8; ++kk) {      // K = 256, steps of 32
      bf16x8 af[4], bwk[4], bwv[4];
#pragma unroll
      for (int m = 0; m < 4; ++m) {
        int row = m * 16 + l15;
        af[m] = *(const bf16x8*)(smem + row * 512 + ((kk * 64 + l4 * 16) ^ (l7 << 4)));
      }
#pragma unroll
      for (int n = 0; n < 4; ++n) {       // fragment-major: 512B coalesced per wave
        size_t off = (((wid * 8 + kk) * 4 + n) * 64 + lane) << 3;
        bwk[n] = *(const bf16x8*)(wkf + off);
        bwv[n] = *(const bf16x8*)(wvf + off);
      }
#pragma unroll
      for (int m = 0; m < 4; ++m)
#pragma unroll
        for (int n = 0; n < 4; ++n) {
          acck[m][n] = MFMA16(af[m], bwk[n], acck[m][n]);
          accv[m][n] = MFMA16(af[m], bwv[n], accv[m][n]);
        }
    }

    __syncthreads();                      // all x-tile LDS reads done

    // LN; write kT -> smem+32K, vT -> smem (over x)
#pragma unroll
    for (int mat = 0; mat < 2; ++mat) {
      const f32x4 (*acc)[4] = mat ? accv : acck;
      const float* gp = mat ? lvg : lkg;
      const float* bp = mat ? lvb : lkb;
      float gv[4], bv[4];
#pragma unroll
      for (int n = 0; n < 4; ++n) { gv[n] = gp[n * 16 + l15]; bv[n] = bp[n * 16 + l15]; }
      char* T = smem + (mat ? 0 : 32768) + wid * 8192;  // [64 d|e][64 s], 128B rows
#pragma unroll
      for (int m = 0; m < 4; ++m) {
        float mu[4], rs[4];
#pragma unroll
        for (int r = 0; r < 4; ++r) {
          float s1 = 0.f, s2 = 0.f;
#pragma unroll
          for (int n = 0; n < 4; ++n) { float x = acc[m][n][r]; s1 += x; s2 += x * x; }
#pragma unroll
          for (int msk = 1; msk < 16; msk <<= 1) {
            s1 += __shfl_xor(s1, msk);
            s2 += __shfl_xor(s2, msk);
          }
          mu[r] = s1 * (1.f / 64.f);
          float var = s2 * (1.f / 64.f) - mu[r] * mu[r];
          rs[r] = rsqrtf(var + LN_EPS);
        }
#pragma unroll
        for (int n = 0; n < 4; ++n) {
          bf16x4 pk;
#pragma unroll
          for (int r = 0; r < 4; ++r)
            pk[r] = f2bf((acc[m][n][r] - mu[r]) * rs[r] * gv[n] + bv[n]);
          int d = n * 16 + l15;           // d&7 == l7
          int sb = m * 32 + l4 * 8;
          *(bf16x4*)(T + d * 128 + (sb ^ (l7 << 4))) = pk;
        }
      }
    }

    __syncthreads();                      // kT + vT ready

    // kv outer product: wave = head
    f32x4 a2[4][4];
#pragma unroll
    for (int fd = 0; fd < 4; ++fd)
#pragma unroll
      for (int n = 0; n < 4; ++n) a2[fd][n] = (f32x4)0.0f;

#pragma unroll
    for (int kk = 0; kk < 2; ++kk) {
      bf16x8 ak[4], bv2[4];
#pragma unroll
      for (int fd = 0; fd < 4; ++fd) {
        int d = fd * 16 + l15;
        ak[fd] = *(const bf16x8*)(smem + 32768 + wid * 8192 + d * 128 +
                                  ((kk * 64 + l4 * 16) ^ (l7 << 4)));
      }
#pragma unroll
      for (int n = 0; n < 4; ++n) {
        int e = n * 16 + l15;
        bv2[n] = *(const bf16x8*)(smem + wid * 8192 + e * 128 +
                                  ((kk * 64 + l4 * 16) ^ (l7 << 4)));
      }
#pragma unroll
      for (int fd = 0; fd < 4; ++fd)
#pragma unroll
        for (int n = 0; n < 4; ++n)
          a2[fd][n] = MFMA16(ak[fd], bv2[n], a2[fd][n]);
    }

    unsigned short* Ph = P + ((size_t)((b * 128 + ptile) * 4 + wid) << 12);
#pragma unroll
    for (int fd = 0; fd < 4; ++fd)
#pragma unroll
      for (int n = 0; n < 4; ++n) {
        bf16x4 pk;
#pragma unroll
        for (int r = 0; r < 4; ++r) pk[r] = f2bf(a2[fd][n][r]);
        *(bf16x4*)(Ph + (fd * 4 + n) * 256 + lane * 4) = pk;
      }
  }
  gridbar(bar + 32);

  // ================= P2: red (all 512 blocks) + prestage P4's x-tile =================
  {
    // prestage P4's seq tile into smem+32768 (kT region dead after P1); overlaps red
    const int b4 = blk >> 7;
    const int srow4 = (blk & 127) * 64;
    stage_x<64>(smem + 32768, seq + (size_t)(b4 * SEQ + srow4) * EMBED, tid);

    int gtid = blk * 256 + tid;           // 131072 = 16384 quads x 8 chunks
    int chunk = gtid & 7;
    int qid = gtid >> 3;
    int b = qid >> 12, h = (qid >> 10) & 3, t4 = qid & 1023;
    const unsigned short* p0 = P + ((size_t)(b * 512 + h) << 12) + t4 * 4;
    float s0 = 0.f, s1 = 0.f, s2 = 0.f, s3 = 0.f;
#pragma unroll
    for (int s = 0; s < 16; ++s) {
      int p = chunk * 16 + s;
      uint2 u = *(const uint2*)(p0 + ((size_t)p << 14));
      s0 += bf2f(u.x & 0xffffu); s1 += bf2f(u.x >> 16);
      s2 += bf2f(u.y & 0xffffu); s3 += bf2f(u.y >> 16);
    }
#pragma unroll
    for (int msk = 1; msk < 8; msk <<= 1) {
      s0 += __shfl_xor(s0, msk); s1 += __shfl_xor(s1, msk);
      s2 += __shfl_xor(s2, msk); s3 += __shfl_xor(s3, msk);
    }
    if (chunk == 0) {
      f32x4 r; r[0] = s0; r[1] = s1; r[2] = s2; r[3] = s3;
      *(f32x4*)(kvf + (qid << 2)) = r;
    }
  }
  gridbar(bar + 64);

  // ================= P3: wc (blocks 0..15 = 4b x 4 o-quarter) =================
  if (blk < 16) {
    const int b = blk >> 2, oq = blk & 3;
    const float invS = 1.f / (float)SEQ;
    char* M1 = smem;                      // [64 o_loc][256 j] bf16, 512B rows, swz

    // phase A: wave = head wj; M1T[o_loc][wj*64+d] = sum_e kv[b,wj,d,e]/S * wo[o][wj*64+e]
    {
      const int wj = wid;
      const float* kvh = kvf + ((b * 4 + wj) << 12);
      f32x4 acc[4][4];
#pragma unroll
      for (int m = 0; m < 4; ++m)
#pragma unroll
        for (int n = 0; n < 4; ++n) acc[m][n] = (f32x4)0.0f;

#pragma unroll
      for (int kk = 0; kk < 2; ++kk) {    // K = 64 (e)
        bf16x8 af[4], bw[4];
#pragma unroll
        for (int m = 0; m < 4; ++m) {
          int base = (m * 4 + kk * 2 + (l4 >> 1)) * 256 +
                     ((l15 >> 2) * 16 + (l4 & 1) * 8) * 4 + (l15 & 3);
          bf16x8 v;
#pragma unroll
          for (int j = 0; j < 8; ++j) v[j] = f2bf(kvh[base + j * 4] * invS);
          af[m] = v;
        }
#pragma unroll
        for (int n = 0; n < 4; ++n) {
          int o = oq * 64 + n * 16 + l15;
          const f32x4* wp = (const f32x4*)(wo + (size_t)o * 256 + wj * 64 + kk * 32 + l4 * 8);
          f32x4 w0 = wp[0], w1 = wp[1];
          bf16x8 v;
          v[0] = f2bf(w0[0]); v[1] = f2bf(w0[1]); v[2] = f2bf(w0[2]); v[3] = f2bf(w0[3]);
          v[4] = f2bf(w1[0]); v[5] = f2bf(w1[1]); v[6] = f2bf(w1[2]); v[7] = f2bf(w1[3]);
          bw[n] = v;
        }
#pragma unroll
        for (int m = 0; m < 4; ++m)
#pragma unroll
          for (int n = 0; n < 4; ++n)
            acc[m][n] = MFMA16(af[m], bw[n], acc[m][n]);
      }
#pragma unroll
      for (int m = 0; m < 4; ++m)
#pragma unroll
        for (int n = 0; n < 4; ++n) {
          int row = n * 16 + l15;         // o_loc
          int jb = (wj * 64 + m * 16 + l4 * 4) * 2;
          bf16x4 pk;
#pragma unroll
          for (int r = 0; r < 4; ++r) pk[r] = f2bf(acc[m][n][r]);
          *(bf16x4*)(M1 + row * 512 + (jb ^ ((row & 7) << 4))) = pk;
        }
    }

    __syncthreads();

    // phase B: wave = i-range wi; Wc[i][o] = sum_j wqT[i][j] * M1T[o_loc][j]
    {
      const int wi = wid;
      f32x4 acc[4][4];
#pragma unroll
      for (int m = 0; m < 4; ++m)
#pragma unroll
        for (int n = 0; n < 4; ++n) acc[m][n] = (f32x4)0.0f;

#pragma unroll
      for (int kk = 0; kk < 8; ++kk) {    // K = 256 (j)
        bf16x8 af[4], bw[4];
#pragma unroll
        for (int m = 0; m < 4; ++m) {
          int i = wi * 64 + m * 16 + l15;
          af[m] = *(const bf16x8*)(wqt + i * 256 + kk * 32 + l4 * 8);
        }
#pragma unroll
        for (int n = 0; n < 4; ++n) {
          int row = n * 16 + l15;
          bw[n] = *(const bf16x8*)(M1 + row * 512 +
                                   ((kk * 64 + l4 * 16) ^ ((row & 7) << 4)));
        }
#pragma unroll
        for (int m = 0; m < 4; ++m)
#pragma unroll
          for (int n = 0; n < 4; ++n)
            acc[m][n] = MFMA16(af[m], bw[n], acc[m][n]);
      }
      const int o6 = oq;
#pragma unroll
      for (int m = 0; m < 4; ++m)
#pragma unroll
        for (int n = 0; n < 4; ++n) {
          int kko = wi * 2 + (m >> 1);
          int laneo = ((m & 1) * 2 + (l4 >> 1)) * 16 + l15;
          int jo = (l4 & 1) * 4;
          bf16x4 pk;
#pragma unroll
          for (int r = 0; r < 4; ++r) pk[r] = f2bf(acc[m][n][r]);
          *(bf16x4*)(wcf + ((size_t)b << 16) +
                     (((((o6 * 8 + kko) * 4 + n) * 64) + laneo) << 3) + jo) = pk;
        }
    }
  }
  gridbar(bar + 96);

  // ================= P4: out (all 512 blocks, 64-row tiles; x pre-staged) ===========
  {
    const int b = blk >> 7;
    const int srow = (blk & 127) * 64;

    const unsigned short* Wf = wcf + ((size_t)b << 16);
    float bov[4];
#pragma unroll
    for (int n = 0; n < 4; ++n) bov[n] = bo[wid * 64 + n * 16 + l15];

    f32x4 acc[4][4];
#pragma unroll
    for (int m = 0; m < 4; ++m)
#pragma unroll
      for (int n = 0; n < 4; ++n) acc[m][n] = (f32x4)0.0f;

#pragma unroll
    for (int kk = 0; kk < 8; ++kk) {      // K = 256; x-tile already in smem+32768
      bf16x8 af[4], bw[4];
#pragma unroll
      for (int m = 0; m < 4; ++m) {
        int row = m * 16 + l15;
        af[m] = *(const bf16x8*)(smem + 32768 + row * 512 +
                                 ((kk * 64 + l4 * 16) ^ (l7 << 4)));
      }
#pragma unroll
      for (int n = 0; n < 4; ++n)         // coalesced 512B per wave, L2-resident
        bw[n] = *(const bf16x8*)(Wf + ((((wid * 8 + kk) * 4 + n) * 64 + lane) << 3));
#pragma unroll
      for (int m = 0; m < 4; ++m)
#pragma unroll
        for (int n = 0; n < 4; ++n)
          acc[m][n] = MFMA16(af[m], bw[n], acc[m][n]);
    }

    float* dst = out + (size_t)(b * SEQ + srow) * EMBED;
#pragma unroll
    for (int m = 0; m < 4; ++m)
#pragma unroll
      for (int n = 0; n < 4; ++n)
#pragma unroll
        for (int r = 0; r < 4; ++r)
          dst[(size_t)(m * 16 + l4 * 4 + r) * EMBED + wid * 64 + n * 16 + l15] =
              acc[m][n][r] + bov[n];
  }
}

extern "C" void kernel_launch(void* const* d_in, const int* in_sizes, int n_in,
                              void* d_out, int out_size, void* d_ws, size_t ws_size,
                              hipStream_t stream) {
  const float* seq = (const float*)d_in[0];
  const float* wq  = (const float*)d_in[1];
  const float* wk  = (const float*)d_in[2];
  const float* wv  = (const float*)d_in[3];
  const float* wo  = (const float*)d_in[4];
  const float* bo  = (const float*)d_in[5];
  const float* lkg = (const float*)d_in[6];
  const float* lkb = (const float*)d_in[7];
  const float* lvg = (const float*)d_in[8];
  const float* lvb = (const float*)d_in[9];
  char* ws = (char*)d_ws;

  unsigned short* wkf = (unsigned short*)(ws + 0);
  unsigned short* wvf = (unsigned short*)(ws + 131072);
  unsigned short* wqt = (unsigned short*)(ws + 262144);
  float*          kvf = (float*)(ws + 524288);
  unsigned short* wcf = (unsigned short*)(ws + 1310720);
  unsigned*       bar = (unsigned*)(ws + 1835008);

  hipMemsetAsync(bar, 0, 512, stream);    // zero grid-barrier counters (captured node)
  gka_mega<<<NBLK, 256, 0, stream>>>(seq, wq, wk, wv, wo, bo, lkg, lkb, lvg, lvb,
                                     wkf, wvf, wqt, kvf, wcf, d_out, bar);
}

// Round 9
// 89.946 us; speedup vs baseline: 4.0869x; 2.1568x over previous
//
#include <hip/hip_runtime.h>
#include <hip/hip_bf16.h>
#include <stdint.h>

// Galerkin self-attention, fused:
//   out = seq @ (wq.T @ blockdiag_h(kv[b,h]) @ wo.T) + bo
//   kv[b,h] = (1/S) * LN(k)_h^T @ LN(v)_h,   k = seq@wk.T, v = seq@wv.T
// v9: back to the multi-kernel structure (r7/r8 mega-kernel: device-wide
//     barriers cost ~35us each on MI355X -> net-negative). vs r6:
//     - gka_prep ELIMINATED: kv reads wk/wv fp32 directly with inline bf16
//       conversion (kv is latency-bound; cvts are free); the wqT transpose
//       moved into gka_red blocks 0-15.  4 kernels, 3 graph gaps.
// ws layout (bytes):
//   262144   wqT bf16 [256 i][256 j]        (written by gka_red blocks 0-15)
//   524288   kvf f32 [4 b][4 h][4096 frag]  (fragment order, by gka_red)
//   1310720  wcf bf16 fragment-major [b][o6][kk][n][lane][8]
// d_out doubles as scratch for P = bf16 partials [4 b][128 p][4 h][4096 frag]
// (16.8MB of the 33.5MB output buffer); gka_out fully overwrites d_out last.

#define EMBED 256
#define SEQ   8192
#define LN_EPS 1e-5f

using bf16x8 = __attribute__((ext_vector_type(8))) short;
using bf16x4 = __attribute__((ext_vector_type(4))) short;
using f32x4  = __attribute__((ext_vector_type(4))) float;

static __device__ __forceinline__ short f2bf(float f) {
  __hip_bfloat16 h = __float2bfloat16(f);
  return __builtin_bit_cast(short, h);
}
static __device__ __forceinline__ float bf2f(uint32_t u) {
  return __uint_as_float(u << 16);
}
static __device__ __forceinline__ bf16x8 cvt8(f32x4 a, f32x4 b) {
  bf16x8 v;
  v[0] = f2bf(a[0]); v[1] = f2bf(a[1]); v[2] = f2bf(a[2]); v[3] = f2bf(a[3]);
  v[4] = f2bf(b[0]); v[5] = f2bf(b[1]); v[6] = f2bf(b[2]); v[7] = f2bf(b[3]);
  return v;
}

#define MFMA16(a, b, c) __builtin_amdgcn_mfma_f32_16x16x32_bf16((a), (b), (c), 0, 0, 0)

// Stage ROWS x 256 fp32 rows -> bf16 LDS [ROWS][256], rows 512B, byte^=(row&7)<<4
template <int ROWS>
static __device__ __forceinline__ void stage_x(char* smem, const float* __restrict__ src, int tid) {
#pragma unroll
  for (int i = 0; i < ROWS / 8; ++i) {
    int g = tid + i * 256;              // 16B-granule index
    int row = g >> 5, c16 = g & 31;
    const f32x4* p = (const f32x4*)(src + row * EMBED + c16 * 8);
    *(bf16x8*)(smem + row * 512 + ((c16 * 16) ^ ((row & 7) << 4))) = cvt8(p[0], p[1]);
  }
}

// ---------------- pass A: k,v GEMM (merged, inline fp32 weights) + LN + kv partial ---
__global__ __launch_bounds__(256, 2)
void gka_kv(const float* __restrict__ seq,
            const float* __restrict__ wk, const float* __restrict__ wv,
            const float* __restrict__ lkg, const float* __restrict__ lkb,
            const float* __restrict__ lvg, const float* __restrict__ lvb,
            unsigned short* __restrict__ P) {
  __shared__ char smem[65536];            // [0,32K): x, later vT; [32K,64K): kT
  const int tid = threadIdx.x;
  const int lane = tid & 63;
  const int wid = tid >> 6;               // wave = head
  const int l15 = lane & 15, l4 = lane >> 4, l7 = lane & 7;
  const int tile = blockIdx.x;            // 512 blocks, 64 tokens each
  const int b = tile >> 7;
  const int ptile = tile & 127;

  stage_x<64>(smem, seq + (size_t)(b * SEQ + ptile * 64) * EMBED, tid);
  __syncthreads();

  // merged k+v GEMM: one pass over x, both weight streams (fp32, L2-resident)
  f32x4 acck[4][4], accv[4][4];
#pragma unroll
  for (int m = 0; m < 4; ++m)
#pragma unroll
    for (int n = 0; n < 4; ++n) { acck[m][n] = (f32x4)0.0f; accv[m][n] = (f32x4)0.0f; }

#pragma unroll
  for (int kk = 0; kk < 8; ++kk) {        // K = 256, steps of 32
    bf16x8 af[4], bwk[4], bwv[4];
#pragma unroll
    for (int m = 0; m < 4; ++m) {
      int row = m * 16 + l15;
      af[m] = *(const bf16x8*)(smem + row * 512 + ((kk * 64 + l4 * 16) ^ (l7 << 4)));
    }
#pragma unroll
    for (int n = 0; n < 4; ++n) {         // fragment pattern, convert inline
      size_t off = (size_t)(wid * 64 + n * 16 + l15) * 256 + kk * 32 + l4 * 8;
      const f32x4* pk = (const f32x4*)(wk + off);
      const f32x4* pv = (const f32x4*)(wv + off);
      bwk[n] = cvt8(pk[0], pk[1]);
      bwv[n] = cvt8(pv[0], pv[1]);
    }
#pragma unroll
    for (int m = 0; m < 4; ++m)
#pragma unroll
      for (int n = 0; n < 4; ++n) {
        acck[m][n] = MFMA16(af[m], bwk[n], acck[m][n]);
        accv[m][n] = MFMA16(af[m], bwv[n], accv[m][n]);
      }
  }

  __syncthreads();                        // all x-tile LDS reads done

  // LN over this wave's 64 head-cols; write kT -> smem+32K, vT -> smem (over x)
#pragma unroll
  for (int mat = 0; mat < 2; ++mat) {
    const f32x4 (*acc)[4] = mat ? accv : acck;     // mat is unroll-static
    const float* gp = mat ? lvg : lkg;
    const float* bp = mat ? lvb : lkb;
    float gv[4], bv[4];
#pragma unroll
    for (int n = 0; n < 4; ++n) { gv[n] = gp[n * 16 + l15]; bv[n] = bp[n * 16 + l15]; }
    char* T = smem + (mat ? 0 : 32768) + wid * 8192;  // [64 d|e][64 s], 128B rows
#pragma unroll
    for (int m = 0; m < 4; ++m) {
      float mu[4], rs[4];
#pragma unroll
      for (int r = 0; r < 4; ++r) {
        float s1 = 0.f, s2 = 0.f;
#pragma unroll
        for (int n = 0; n < 4; ++n) { float x = acc[m][n][r]; s1 += x; s2 += x * x; }
#pragma unroll
        for (int msk = 1; msk < 16; msk <<= 1) {
          s1 += __shfl_xor(s1, msk);
          s2 += __shfl_xor(s2, msk);
        }
        mu[r] = s1 * (1.f / 64.f);
        float var = s2 * (1.f / 64.f) - mu[r] * mu[r];
        rs[r] = rsqrtf(var + LN_EPS);
      }
#pragma unroll
      for (int n = 0; n < 4; ++n) {
        bf16x4 pk;
#pragma unroll
        for (int r = 0; r < 4; ++r)
          pk[r] = f2bf((acc[m][n][r] - mu[r]) * rs[r] * gv[n] + bv[n]);
        int d = n * 16 + l15;             // d&7 == l7
        int sb = m * 32 + l4 * 8;         // byte offset of s0 = m*16+l4*4
        *(bf16x4*)(T + d * 128 + (sb ^ (l7 << 4))) = pk;
      }
    }
  }

  __syncthreads();                        // kT + vT ready

  // kv outer product: wave = head; kv[d][e] += sum_s kT[d][s] * vT[e][s]
  f32x4 a2[4][4];
#pragma unroll
  for (int fd = 0; fd < 4; ++fd)
#pragma unroll
    for (int n = 0; n < 4; ++n) a2[fd][n] = (f32x4)0.0f;

#pragma unroll
  for (int kk = 0; kk < 2; ++kk) {        // 64 tokens = 2 K-steps
    bf16x8 ak[4], bv2[4];
#pragma unroll
    for (int fd = 0; fd < 4; ++fd) {
      int d = fd * 16 + l15;
      ak[fd] = *(const bf16x8*)(smem + 32768 + wid * 8192 + d * 128 +
                                ((kk * 64 + l4 * 16) ^ (l7 << 4)));
    }
#pragma unroll
    for (int n = 0; n < 4; ++n) {
      int e = n * 16 + l15;
      bv2[n] = *(const bf16x8*)(smem + wid * 8192 + e * 128 +
                                ((kk * 64 + l4 * 16) ^ (l7 << 4)));
    }
#pragma unroll
    for (int fd = 0; fd < 4; ++fd)
#pragma unroll
      for (int n = 0; n < 4; ++n)
        a2[fd][n] = MFMA16(ak[fd], bv2[n], a2[fd][n]);
  }

  // store P in raw fragment order: flat = (fd*4+n)*256 + lane*4 + r  (coalesced 512B)
  unsigned short* Ph = P + ((size_t)((b * 128 + ptile) * 4 + wid) << 12);
#pragma unroll
  for (int fd = 0; fd < 4; ++fd)
#pragma unroll
    for (int n = 0; n < 4; ++n) {
      bf16x4 pk;
#pragma unroll
      for (int r = 0; r < 4; ++r) pk[r] = f2bf(a2[fd][n][r]);
      *(bf16x4*)(Ph + (fd * 4 + n) * 256 + lane * 4) = pk;
    }
}

// ---------------- reduce: kvf = sum_p P;  blocks 0-15 also build wqT -----------------
__global__ __launch_bounds__(256)
void gka_red(const unsigned short* __restrict__ P, float* __restrict__ kvf,
             const float* __restrict__ wq, unsigned short* __restrict__ wqt) {
  __shared__ unsigned short T[64 * 66];
  int blk = blockIdx.x, tid = threadIdx.x;
  {
    int gtid = blk * 256 + tid;               // 131072 = 16384 quads x 8 chunks
    int chunk = gtid & 7;
    int qid = gtid >> 3;                      // (b<<12) | (h<<10) | t4
    int b = qid >> 12, h = (qid >> 10) & 3, t4 = qid & 1023;
    const unsigned short* p0 = P + ((size_t)(b * 512 + h) << 12) + t4 * 4;
    float s0 = 0.f, s1 = 0.f, s2 = 0.f, s3 = 0.f;
#pragma unroll
    for (int s = 0; s < 16; ++s) {
      int p = chunk * 16 + s;
      uint2 u = *(const uint2*)(p0 + ((size_t)p << 14));
      s0 += bf2f(u.x & 0xffffu); s1 += bf2f(u.x >> 16);
      s2 += bf2f(u.y & 0xffffu); s3 += bf2f(u.y >> 16);
    }
#pragma unroll
    for (int msk = 1; msk < 8; msk <<= 1) {
      s0 += __shfl_xor(s0, msk); s1 += __shfl_xor(s1, msk);
      s2 += __shfl_xor(s2, msk); s3 += __shfl_xor(s3, msk);
    }
    if (chunk == 0) {
      f32x4 r; r[0] = s0; r[1] = s1; r[2] = s2; r[3] = s3;
      *(f32x4*)(kvf + (qid << 2)) = r;
    }
  }

  if (blk < 16) {                         // 64x64 tile transpose wqt[i][j] = wq[j][i]
    int ti = blk >> 2, tj = blk & 3;
#pragma unroll
    for (int it = 0; it < 4; ++it) {
      int g = tid + it * 256;               // 1024 granules of 4 floats
      int jl = g >> 4, g4 = g & 15;
      f32x4 f = *(const f32x4*)(wq + (tj * 64 + jl) * 256 + ti * 64 + g4 * 4);
#pragma unroll
      for (int q = 0; q < 4; ++q) T[jl * 66 + g4 * 4 + q] = (unsigned short)f2bf(f[q]);
    }
    __syncthreads();
#pragma unroll
    for (int it = 0; it < 2; ++it) {
      int g = tid + it * 256;               // 512 output groups of 8
      int il = g >> 3, j8 = g & 7;
      bf16x8 v;
#pragma unroll
      for (int q = 0; q < 8; ++q) v[q] = (short)T[(j8 * 8 + q) * 66 + il];
      *(bf16x8*)(wqt + (ti * 64 + il) * 256 + tj * 64 + j8 * 8) = v;
    }
  }
}

// ---------------- pass B (merged m1+wc): per (b, o-half) block ----------------------
// phase 1: M1T[o_loc][j=h*64+d] = sum_e kv[b,h,d,e]/S * wo[o][h*64+e]  -> LDS (swz)
// phase 2: WcT frag-major: Wc[i][o] = sum_j wqT[i][j] * M1T[o_loc][j]
__global__ __launch_bounds__(512)
void gka_wc(const float* __restrict__ kvf, const float* __restrict__ wo,
            const unsigned short* __restrict__ wqt, unsigned short* __restrict__ wcf) {
  __shared__ char M1[65536];              // [128 o_loc][256 j] bf16, 512B rows, swz
  const int tid = threadIdx.x;
  const int lane = tid & 63;
  const int wid = tid >> 6;               // 8 waves
  const int l15 = lane & 15, l4 = lane >> 4;
  const int blk = blockIdx.x;             // 8 = 4b x 2 o-half
  const int b = blk >> 1, oh = blk & 1;
  const float invS = 1.f / (float)SEQ;

  // ---- phase 1: wave -> (wo_t = wid>>2 o-64-range, wj = wid&3 head) ----
  {
    const int wo_t = wid >> 2, wj = wid & 3;
    const float* kvh = kvf + ((b * 4 + wj) << 12);
    f32x4 acc[4][4];
#pragma unroll
    for (int m = 0; m < 4; ++m)
#pragma unroll
      for (int n = 0; n < 4; ++n) acc[m][n] = (f32x4)0.0f;

#pragma unroll
    for (int kk = 0; kk < 2; ++kk) {      // K = 64 (e)
      bf16x8 af[4], bw[4];
#pragma unroll
      for (int m = 0; m < 4; ++m) {
        // gather (d = m*16+l15, e = kk*32+l4*8+j) from kv fragment layout
        int base = (m * 4 + kk * 2 + (l4 >> 1)) * 256 +
                   ((l15 >> 2) * 16 + (l4 & 1) * 8) * 4 + (l15 & 3);
        bf16x8 v;
#pragma unroll
        for (int j = 0; j < 8; ++j) v[j] = f2bf(kvh[base + j * 4] * invS);
        af[m] = v;
      }
#pragma unroll
      for (int n = 0; n < 4; ++n) {
        int o = oh * 128 + wo_t * 64 + n * 16 + l15;
        const f32x4* wp = (const f32x4*)(wo + (size_t)o * 256 + wj * 64 + kk * 32 + l4 * 8);
        bw[n] = cvt8(wp[0], wp[1]);
      }
#pragma unroll
      for (int m = 0; m < 4; ++m)
#pragma unroll
        for (int n = 0; n < 4; ++n)
          acc[m][n] = MFMA16(af[m], bw[n], acc[m][n]);
    }
    // store to LDS M1T: row = o_loc, col j = wj*64 + m*16 + l4*4 + r (bf16x4), swz
#pragma unroll
    for (int m = 0; m < 4; ++m)
#pragma unroll
      for (int n = 0; n < 4; ++n) {
        int row = wo_t * 64 + n * 16 + l15;
        int jb = (wj * 64 + m * 16 + l4 * 4) * 2;
        bf16x4 pk;
#pragma unroll
        for (int r = 0; r < 4; ++r) pk[r] = f2bf(acc[m][n][r]);
        *(bf16x4*)(M1 + row * 512 + (jb ^ ((row & 7) << 4))) = pk;
      }
  }

  __syncthreads();

  // ---- phase 2: wave -> (wi = wid>>1 i-64-range, wo2 = wid&1 o-64-range) ----
  {
    const int wi = wid >> 1, wo2 = wid & 1;
    f32x4 acc[4][4];
#pragma unroll
    for (int m = 0; m < 4; ++m)
#pragma unroll
      for (int n = 0; n < 4; ++n) acc[m][n] = (f32x4)0.0f;

#pragma unroll
    for (int kk = 0; kk < 8; ++kk) {      // K = 256 (j)
      bf16x8 af[4], bw[4];
#pragma unroll
      for (int m = 0; m < 4; ++m) {
        int i = wi * 64 + m * 16 + l15;
        af[m] = *(const bf16x8*)(wqt + i * 256 + kk * 32 + l4 * 8);
      }
#pragma unroll
      for (int n = 0; n < 4; ++n) {
        int row = wo2 * 64 + n * 16 + l15;
        bw[n] = *(const bf16x8*)(M1 + row * 512 +
                                 ((kk * 64 + l4 * 16) ^ ((row & 7) << 4)));
      }
#pragma unroll
      for (int m = 0; m < 4; ++m)
#pragma unroll
        for (int n = 0; n < 4; ++n)
          acc[m][n] = MFMA16(af[m], bw[n], acc[m][n]);
    }
    // store to fragment-major wcf for gka_out
    const int o6 = oh * 2 + wo2;
#pragma unroll
    for (int m = 0; m < 4; ++m)
#pragma unroll
      for (int n = 0; n < 4; ++n) {
        int kko = wi * 2 + (m >> 1);
        int laneo = ((m & 1) * 2 + (l4 >> 1)) * 16 + l15;
        int jo = (l4 & 1) * 4;
        bf16x4 pk;
#pragma unroll
        for (int r = 0; r < 4; ++r) pk[r] = f2bf(acc[m][n][r]);
        *(bf16x4*)(wcf + ((size_t)b << 16) +
                   (((((o6 * 8 + kko) * 4 + n) * 64) + laneo) << 3) + jo) = pk;
      }
  }
}

// ---------------- pass C: out = seq @ Wc[b] + bo  (1024 x 32-token tiles, LDS) -------
__global__ __launch_bounds__(256, 4)
void gka_out(const float* __restrict__ seq, const unsigned short* __restrict__ wcf,
             const float* __restrict__ bo, float* __restrict__ out) {
  __shared__ char smem[16384];
  const int tid = threadIdx.x;
  const int lane = tid & 63;
  const int wid = tid >> 6;               // wave -> o-range (64 cols)
  const int l15 = lane & 15, l4 = lane >> 4, l7 = lane & 7;
  const int tile = blockIdx.x;            // 1024 = 4b x 256 tiles of 32 rows
  const int b = tile >> 8;
  const int srow = (tile & 255) * 32;

  stage_x<32>(smem, seq + (size_t)(b * SEQ + srow) * EMBED, tid);

  const unsigned short* Wf = wcf + ((size_t)b << 16);
  float bov[4];
#pragma unroll
  for (int n = 0; n < 4; ++n) bov[n] = bo[wid * 64 + n * 16 + l15];

  f32x4 acc[2][4];
#pragma unroll
  for (int m = 0; m < 2; ++m)
#pragma unroll
    for (int n = 0; n < 4; ++n) acc[m][n] = (f32x4)0.0f;

  __syncthreads();

#pragma unroll
  for (int kk = 0; kk < 8; ++kk) {        // K = 256, no barriers
    bf16x8 af[2], bw[4];
#pragma unroll
    for (int m = 0; m < 2; ++m) {
      int row = m * 16 + l15;
      af[m] = *(const bf16x8*)(smem + row * 512 + ((kk * 64 + l4 * 16) ^ (l7 << 4)));
    }
#pragma unroll
    for (int n = 0; n < 4; ++n)           // coalesced 512B per wave, L2-resident
      bw[n] = *(const bf16x8*)(Wf + ((((wid * 8 + kk) * 4 + n) * 64 + lane) << 3));
#pragma unroll
    for (int m = 0; m < 2; ++m)
#pragma unroll
      for (int n = 0; n < 4; ++n)
        acc[m][n] = MFMA16(af[m], bw[n], acc[m][n]);
  }

  float* dst = out + (size_t)(b * SEQ + srow) * EMBED;
#pragma unroll
  for (int m = 0; m < 2; ++m)
#pragma unroll
    for (int n = 0; n < 4; ++n)
#pragma unroll
      for (int r = 0; r < 4; ++r)
        dst[(size_t)(m * 16 + l4 * 4 + r) * EMBED + wid * 64 + n * 16 + l15] =
            acc[m][n][r] + bov[n];
}

extern "C" void kernel_launch(void* const* d_in, const int* in_sizes, int n_in,
                              void* d_out, int out_size, void* d_ws, size_t ws_size,
                              hipStream_t stream) {
  const float* seq = (const float*)d_in[0];
  const float* wq  = (const float*)d_in[1];
  const float* wk  = (const float*)d_in[2];
  const float* wv  = (const float*)d_in[3];
  const float* wo  = (const float*)d_in[4];
  const float* bo  = (const float*)d_in[5];
  const float* lkg = (const float*)d_in[6];
  const float* lkb = (const float*)d_in[7];
  const float* lvg = (const float*)d_in[8];
  const float* lvb = (const float*)d_in[9];
  float* out = (float*)d_out;
  char* ws = (char*)d_ws;

  unsigned short* wqt = (unsigned short*)(ws + 262144);
  float*          kvf = (float*)(ws + 524288);
  unsigned short* wcf = (unsigned short*)(ws + 1310720);
  unsigned short* P   = (unsigned short*)d_out;   // 16.8MB partials, overwritten by gka_out

  gka_kv<<<512, 256, 0, stream>>>(seq, wk, wv, lkg, lkb, lvg, lvb, P);
  gka_red<<<512, 256, 0, stream>>>(P, kvf, wq, wqt);
  gka_wc<<<8, 512, 0, stream>>>(kvf, wo, wqt, wcf);
  gka_out<<<1024, 256, 0, stream>>>(seq, wcf, bo, out);
}